// Round 8
// baseline (197.446 us; speedup 1.0000x reference)
//
#include <hip/hip_runtime.h>

constexpr int TN   = 100000;
constexpr int NCH  = 4000;          // chunks of the time series
constexpr int CLEN = 25;            // NCH*CLEN == TN
constexpr int WARM = 12;            // warm-up steps (contraction forgets init)
constexpr int WPB  = 4;             // waves per block
constexpr int NBLK = NCH / WPB;     // 1000 -> ~4 blocks/CU, 4 waves/SIMD
constexpr int MAXS = WARM + CLEN;   // 37

constexpr float LOG2E = 1.4426950408889634f;
constexpr float PI_F  = 3.1415926f;

typedef float v2f __attribute__((ext_vector_type(2)));

// DPP row-rotate by N within 16-lane rows (direction auto-detected at runtime)
#define ROR(src, N) __int_as_float(__builtin_amdgcn_mov_dpp( \
    __float_as_int(src), 0x120 + (N), 0xF, 0xF, false))

// 16-lane ring reduction via rotate-adds (direction-agnostic), stays on VALU
#define RING16(v) { v += ROR(v,1); v += ROR(v,2); v += ROR(v,4); v += ROR(v,8); }

static __device__ __forceinline__ v2f sp(float x) { return (v2f){x, x}; }

#define REP15(M) M(1) M(2) M(3) M(4) M(5) M(6) M(7) M(8) M(9) M(10) M(11) \
                 M(12) M(13) M(14) M(15)

// ---------------------------------------------------------------------------
// k_main — zero-cross-lane recursion, occupancy-corrected.
//
// R7 MEASURED (the first clean k_main row): 42.6us, VALUBusy 61%, VGPR 80,
// Occupancy 14.75%, FETCH 0.5MB/WRITE ~0, conflicts 0. Issue-model match:
// 2 waves/SIMD x 62 steps x ~252 cy = 62k VALU-busy cycles = exactly the
// measured 61% of 102k cy. -> Pure VALU-issue workload at 61% duty; the 39%
// idle is simultaneous chain-stall of the only 2 resident waves. Grid (500
// blocks) was the limiter, not registers (80 VGPR allows 6 waves/SIMD).
// THIS ROUND (one variable): NCH=4000/CLEN=25 -> NBLK=1000 -> 4 blocks/CU
// -> 4 waves/SIMD. +19% warm-tax, but issue slots fill: predicted ~16-20us.
//
// Layout (proven R7, absmax 0.0): state per lane = PAIR (y_i, y_{i+16}),
// i=lane&15, replicated across the four 16-rows. Row-rotations (DPP ROR)
// feed every y_k to every lane; each lane computes BOTH its outputs' full
// 32-element dots with 32 v_pk_fma_f32. Weights: 64 named v2f (wa/wb = W
// k-low/k-high, ua/ub = W2). S and N2 via per-lane pair-sum + RING16 (rows
// replicated => full sum in every lane; no readlane/bpermute/DS). Renorm
// every step by rcp(S) (rcp already needed for the loss; scale cancels in
// corr*N2/S). Only DS op per step: wave-uniform cts broadcast read.
// Loss math (proven): loss_t = corr * N2 / S on CENTERED u; chunk 0 starts
// exactly from pi; others warm-start WARM=12 early (CLEN=25 proven in R6).
// Block tail: 4-wave LDS reduce -> one atomicAdd per block (out zeroed by
// memsetAsync in kernel_launch).
// ---------------------------------------------------------------------------
__global__ __launch_bounds__(256, 4) void k_main(
    const float* __restrict__ obs2, const float* __restrict__ obs1,
    const float* __restrict__ mean_p, const float* __restrict__ var_p,
    const float* __restrict__ bate_p, const float* __restrict__ pi_p,
    const float* __restrict__ aij, float* __restrict__ out)
{
  const int w = threadIdx.x >> 6, lane = threadIdx.x & 63;
  const int wv = blockIdx.x * WPB + w;
  const int i  = lane & 15;

  __shared__ __align__(16) float Wsh[2][32][32];   // [sel][k][j]
  __shared__ float cts[WPB][MAXS + 2];
  __shared__ float bsum[WPB];

  // --- block-cooperative prep of W, W2 into LDS (once; proven) ---
  {
    const int tid = threadIdx.x;
    const int jj = tid & 31, ig = tid >> 5;
    float vjq  = var_p[jj];
    float i2vq = 0.5f / vjq;
    float norm = rsqrtf(2.0f * PI_F * vjq);
    float Aj   = norm * expf(mean_p[jj] * i2vq);
    float bate = bate_p[0];
#pragma unroll
    for (int mm = 0; mm < 4; ++mm) {
      int ii = ig * 4 + mm;
      float Bij = expf(-bate * mean_p[ii] * i2vq);
      float wq = aij[ii * 32 + jj] * Aj * Bij;
      Wsh[0][ii][jj] = wq;
      Wsh[1][ii][jj] = wq * Aj * Bij;
    }
  }

  // --- exponent constants (pair-indexed): slopes for outputs i and i+16 ---
  float iva = 0.5f / var_p[i];
  float ivb = 0.5f / var_p[i + 16];
  float s2 = iva + ivb;
  RING16(s2)                              // sum over row = sum over all 32 j
  const float mbar = s2 * 0.03125f;
  const float sx = (iva - mbar) * LOG2E;  // centered slope, output i
  const float sy = (ivb - mbar) * LOG2E;  // centered slope, output i+16
  const float Mc = mbar * LOG2E;          // scalar corr slope

  // --- stage cts for this wave's range ---
  const int t0 = wv * CLEN;
  const int tw = (t0 > WARM) ? (t0 - WARM) : 0;
  const int n  = t0 + CLEN - tw;
  const int warmsteps = t0 - tw;
  {
    float bate = bate_p[0];
    for (int l = lane; l < n; l += 64)
      cts[w][l] = obs2[tw + l] - bate * obs1[tw + l];
  }
  __syncthreads();   // Wsh ready

  // --- rotation direction probe (proven) ---
  int dird;
  { int p = __builtin_amdgcn_mov_dpp(i, 0x121, 0xF, 0xF, false);
    dird = (p - i) & 15; }

  // --- 64 named v2f weight pairs (128 VGPR, register-resident) ---
  // wa_d/ua_d: k1=(i+d*dird)&15 (fed by rotated Y.x);  wb_d/ub_d: k2=k1+16
  // (fed by rotated Y.y). Pair components = output columns (i, i+16).
#define DECLW(d) v2f wa##d, wb##d, ua##d, ub##d;
  DECLW(0) REP15(DECLW)
#undef DECLW
#define LOADW(d) {                                                            \
    int k1 = (i + (d) * dird) & 15;                                           \
    int k2 = k1 + 16;                                                         \
    wa##d = (v2f){Wsh[0][k1][i], Wsh[0][k1][i + 16]};                         \
    wb##d = (v2f){Wsh[0][k2][i], Wsh[0][k2][i + 16]};                         \
    ua##d = (v2f){Wsh[1][k1][i], Wsh[1][k1][i + 16]};                         \
    ub##d = (v2f){Wsh[1][k2][i], Wsh[1][k2][i + 16]}; }
  LOADW(0) REP15(LOADW)
#undef LOADW

  // start state: exact pi pair if warm-up reaches t=0, else uniform
  float Yx = (tw == 0) ? pi_p[i]      : 0.03125f;
  float Yy = (tw == 0) ? pi_p[i + 16] : 0.03125f;

  // stanzas: W-only (warm) and W+W2 (main). Splat operands fold to op_sel.
#define WST(d) { float rx = ROR(Yx, d), ry = ROR(Yy, d);                      \
    D0 += sp(rx) * wa##d; D1 += sp(ry) * wb##d; }
#define MST(d) { float rx = ROR(Yx, d), ry = ROR(Yy, d);                      \
    D0 += sp(rx) * wa##d; D1 += sp(ry) * wb##d;                               \
    E0 += sp(rx) * ua##d; E1 += sp(ry) * ub##d; }

  // ---- warm-up: W-dot only; chain is pure VALU (DPP + pk_fma) ----
  for (int s = 0; s < warmsteps; ++s) {
    float ct = cts[w][s];
    float ex = exp2f(-ct * sx), ey = exp2f(-ct * sy);
    v2f D0 = (v2f){0.f, 0.f}, D1 = (v2f){0.f, 0.f};
    D0 += sp(Yx) * wa0; D1 += sp(Yy) * wb0;
    REP15(WST)
    v2f D = D0 + D1;
    float ynx = ex * D.x, yny = ey * D.y;
    float s_ = ynx + yny;
    RING16(s_)                           // full S, every lane
    float r = __builtin_amdgcn_rcpf(s_);
    Yx = ynx * r; Yy = yny * r;          // renorm every step (free)
  }

  // ---- owned range: loss via label-free sums, all in-lane/in-row ----
  float lossacc = 0.f;
  for (int q = 0; q < CLEN; ++q) {
    float ct   = cts[w][warmsteps + q];
    float ex = exp2f(-ct * sx), ey = exp2f(-ct * sy);
    float corr = exp2f(-ct * Mc);
    v2f D0 = (v2f){0.f, 0.f}, D1 = (v2f){0.f, 0.f};
    v2f E0 = (v2f){0.f, 0.f}, E1 = (v2f){0.f, 0.f};
    D0 += sp(Yx) * wa0; D1 += sp(Yy) * wb0;
    E0 += sp(Yx) * ua0; E1 += sp(Yy) * ub0;
    REP15(MST)
    v2f D = D0 + D1, E = E0 + E1;
    float ynx = ex * D.x,        yny = ey * D.y;          // next state pair
    float vx  = (ex * ex) * E.x, vy  = (ey * ey) * E.y;   // side-band pair
    float s_ = ynx + yny;
    RING16(s_)                           // S  = sum_m y'_m   (every lane)
    float n_ = vx + vy;
    RING16(n_)                           // N2 = sum_m u^2 (W2^T y)_m
    float r = __builtin_amdgcn_rcpf(s_);
    lossacc += corr * n_ * r;
    Yx = ynx * r; Yy = yny * r;          // renorm every step
  }
#undef WST
#undef MST

  // ---- block reduce + one atomic per block (lossacc same in all lanes) ----
  if (lane == 0) bsum[w] = lossacc;
  __syncthreads();
  if (threadIdx.x == 0)
    atomicAdd(out, (bsum[0] + bsum[1]) + (bsum[2] + bsum[3]));
}

extern "C" void kernel_launch(void* const* d_in, const int* in_sizes, int n_in,
                              void* d_out, int out_size, void* d_ws, size_t ws_size,
                              hipStream_t stream)
{
  (void)in_sizes; (void)n_in; (void)ws_size; (void)d_ws;
  const float* obs2 = (const float*)d_in[0];
  const float* obs1 = (const float*)d_in[1];
  const float* mean = (const float*)d_in[2];
  const float* var  = (const float*)d_in[3];
  const float* bate = (const float*)d_in[4];
  const float* pi   = (const float*)d_in[5];
  const float* aij  = (const float*)d_in[6];
  float* out = (float*)d_out;

  hipMemsetAsync(out, 0, sizeof(float) * out_size, stream);
  k_main<<<NBLK, 256, 0, stream>>>(obs2, obs1, mean, var, bate, pi, aij, out);
}

// Round 9
// 92.478 us; speedup vs baseline: 2.1351x; 2.1351x over previous
//
#include <hip/hip_runtime.h>

constexpr int TN   = 100000;
constexpr int NCH  = 4000;          // chunks of the time series
constexpr int CLEN = 25;            // NCH*CLEN == TN
constexpr int WARM = 12;            // warm-up steps (contraction forgets init)
constexpr int WPB  = 4;             // waves per block
constexpr int NBLK = NCH / WPB;     // 1000 -> ~4 blocks/CU, 4 waves/SIMD
constexpr int MAXS = WARM + CLEN;   // 37

constexpr float LOG2E = 1.4426950408889634f;
constexpr float PI_F  = 3.1415926f;

typedef float v2f __attribute__((ext_vector_type(2)));

// DPP row-rotate by N within 16-lane rows (direction auto-detected at runtime)
#define ROR(src, N) __int_as_float(__builtin_amdgcn_mov_dpp( \
    __float_as_int(src), 0x120 + (N), 0xF, 0xF, false))

// 16-lane ring reduction via rotate-adds (direction-agnostic), stays on VALU
#define RING16(v) { v += ROR(v,1); v += ROR(v,2); v += ROR(v,4); v += ROR(v,8); }

static __device__ __forceinline__ v2f sp(float x) { return (v2f){x, x}; }

#define REP15(M) M(1) M(2) M(3) M(4) M(5) M(6) M(7) M(8) M(9) M(10) M(11) \
                 M(12) M(13) M(14) M(15)

// ---------------------------------------------------------------------------
// k_main — "QSPLIT": quarter-work zero-redundancy step, proven primitives only.
//
// EVIDENCE LADDER:
//  R7 (pair layout, zero DS): 42.6us, VALUBusy 61% @2 waves/SIMD, VGPR 80 —
//    but ~500 issue-cy/step: 4x redundant FMA (64 pk_fma) + 64 v2f weights
//    living in AGPRs (v_accvgpr_read per use; VGPR budget from bounds(256,2)).
//  R8 ERRATA: __launch_bounds__(256,4) is a HARD 128-VGPR clamp -> scratch
//    spill catastrophe (FETCH 85MB/WRITE 93MB, 134-152us). Never tighten the
//    2nd arg on a register-heavy kernel.
//
// THIS VERSION cuts per-step issue ~4x:
//  * bit5 (h) splits the k-half, bit4 (b4) splits the MATRIX (W vs W2):
//    each lane computes a 16-term partial of ONE matrix for its output pair
//    (i, i+16): 16 pk_fma/step, 16 v2f weights = 32 VGPR (register-resident).
//  * combine with proven __shfl_xor only:
//      F = P + shfl_xor(P,32)   -> full dot of own matrix (k-halves joined)
//      G = shfl_xor(F,16)       -> partner matrix's full dot
//      D = b4 ? G : F (W dot)   E = b4 ? F : G (W2 dot)  — identical in all
//    lanes of equal i -> state stays row-replicated.
//  * S  = RING16(ynx+yny), N2 = RING16(vx+vy) (pure DPP, every lane).
//  * renorm every step by rcp(S) (needed for loss anyway; scale cancels).
// Per step: 15 ROR + 16 pk_fma + 4 shfl_xor + 2 RING16 + 3 exp2 + rcp + misc
// ~= 62 VALU instr (~125 issue-cy) + 4 DS ops. Issue floor at 148k wave-steps
// ~= 7.5us; chain (~330cy, 2 serial DS levels) hidden by 4 waves/SIMD.
//
// Loss math (proven): loss_t = corr * N2 / S on CENTERED u; chunk 0 starts
// exactly from pi; others warm-start WARM=12 early (CLEN=25 proven, absmax 0).
// Block tail: lossacc is lane-uniform; 4-wave LDS reduce -> one atomicAdd.
// ---------------------------------------------------------------------------
__global__ __launch_bounds__(256, 2) void k_main(
    const float* __restrict__ obs2, const float* __restrict__ obs1,
    const float* __restrict__ mean_p, const float* __restrict__ var_p,
    const float* __restrict__ bate_p, const float* __restrict__ pi_p,
    const float* __restrict__ aij, float* __restrict__ out)
{
  const int w = threadIdx.x >> 6, lane = threadIdx.x & 63;
  const int wv = blockIdx.x * WPB + w;
  const int i  = lane & 15;
  const int b4 = (lane >> 4) & 1;     // matrix selector: 0 = W, 1 = W2
  const int h  = lane >> 5;           // k-half selector
  const int kb = h * 16;

  __shared__ __align__(16) float Wsh[2][32][32];   // [sel][k][j]
  __shared__ float cts[WPB][MAXS + 2];
  __shared__ float bsum[WPB];

  // --- block-cooperative prep of W, W2 into LDS (once; proven) ---
  {
    const int tid = threadIdx.x;
    const int jj = tid & 31, ig = tid >> 5;
    float vjq  = var_p[jj];
    float i2vq = 0.5f / vjq;
    float norm = rsqrtf(2.0f * PI_F * vjq);
    float Aj   = norm * expf(mean_p[jj] * i2vq);
    float bate = bate_p[0];
#pragma unroll
    for (int mm = 0; mm < 4; ++mm) {
      int ii = ig * 4 + mm;
      float Bij = expf(-bate * mean_p[ii] * i2vq);
      float wq = aij[ii * 32 + jj] * Aj * Bij;
      Wsh[0][ii][jj] = wq;
      Wsh[1][ii][jj] = wq * Aj * Bij;
    }
  }

  // --- exponent constants (pair-indexed, proven R7) ---
  float iva = 0.5f / var_p[i];
  float ivb = 0.5f / var_p[i + 16];
  float s2 = iva + ivb;
  RING16(s2)                              // sum over row = sum over all 32 j
  const float mbar = s2 * 0.03125f;
  const float sx = (iva - mbar) * LOG2E;  // centered slope, output i
  const float sy = (ivb - mbar) * LOG2E;  // centered slope, output i+16
  const float Mc = mbar * LOG2E;          // scalar corr slope

  // --- stage cts for this wave's range ---
  const int t0 = wv * CLEN;
  const int tw = (t0 > WARM) ? (t0 - WARM) : 0;
  const int n  = t0 + CLEN - tw;
  const int warmsteps = t0 - tw;
  {
    float bate = bate_p[0];
    for (int l = lane; l < n; l += 64)
      cts[w][l] = obs2[tw + l] - bate * obs1[tw + l];
  }
  __syncthreads();   // Wsh ready

  // --- rotation direction probe (proven) ---
  int dird;
  { int p = __builtin_amdgcn_mov_dpp(i, 0x121, 0xF, 0xF, false);
    dird = (p - i) & 15; }

  // --- 16 named v2f weights: this lane's matrix (b4), k-half (h), pair (i) ---
  const float (*Ms)[32] = Wsh[b4];
#define DECLW(d) v2f m##d;
  DECLW(0) REP15(DECLW)
#undef DECLW
#define LOADW(d) {                                                            \
    int k = kb + ((i + (d) * dird) & 15);                                     \
    m##d = (v2f){Ms[k][i], Ms[k][i + 16]}; }
  LOADW(0) REP15(LOADW)
#undef LOADW

  // start state: exact pi pair if warm-up reaches t=0, else uniform
  float Yx = (tw == 0) ? pi_p[i]      : 0.03125f;
  float Yy = (tw == 0) ? pi_p[i + 16] : 0.03125f;

  // partial-dot stanza: d-th rotation of this lane's k-half source
#define STZ(d) { float rv = ROR(Ysel, d);                                     \
    if ((d) & 1) PB += sp(rv) * m##d; else PA += sp(rv) * m##d; }

  // ---- warm-up: recursion only (D needed; E computed but unused) ----
  for (int s = 0; s < warmsteps; ++s) {
    float ct = cts[w][s];
    float ex = exp2f(-ct * sx), ey = exp2f(-ct * sy);
    float Ysel = h ? Yy : Yx;
    v2f PA = sp(Ysel) * m0, PB = (v2f){0.f, 0.f};
    REP15(STZ)
    v2f P = PA + PB;
    float Fx = P.x + __shfl_xor(P.x, 32);   // full dot, own matrix
    float Fy = P.y + __shfl_xor(P.y, 32);
    float Gx = __shfl_xor(Fx, 16);          // partner matrix's dot
    float Gy = __shfl_xor(Fy, 16);
    float Dx = b4 ? Gx : Fx, Dy = b4 ? Gy : Fy;   // W dot, every lane
    float ynx = ex * Dx, yny = ey * Dy;
    float s_ = ynx + yny;
    RING16(s_)
    float r = __builtin_amdgcn_rcpf(s_);
    Yx = ynx * r; Yy = yny * r;             // renorm every step
  }

  // ---- owned range: loss via label-free sums ----
  float lossacc = 0.f;
  for (int q = 0; q < CLEN; ++q) {
    float ct   = cts[w][warmsteps + q];
    float ex = exp2f(-ct * sx), ey = exp2f(-ct * sy);
    float corr = exp2f(-ct * Mc);
    float Ysel = h ? Yy : Yx;
    v2f PA = sp(Ysel) * m0, PB = (v2f){0.f, 0.f};
    REP15(STZ)
    v2f P = PA + PB;
    float Fx = P.x + __shfl_xor(P.x, 32);
    float Fy = P.y + __shfl_xor(P.y, 32);
    float Gx = __shfl_xor(Fx, 16);
    float Gy = __shfl_xor(Fy, 16);
    float Dx = b4 ? Gx : Fx, Dy = b4 ? Gy : Fy;   // W dot
    float Ex = b4 ? Fx : Gx, Ey = b4 ? Fy : Gy;   // W2 dot
    float ynx = ex * Dx,        yny = ey * Dy;          // next state pair
    float vx  = (ex * ex) * Ex, vy  = (ey * ey) * Ey;   // side-band pair
    float s_ = ynx + yny;
    RING16(s_)                           // S  = sum_m y'_m   (every lane)
    float n_ = vx + vy;
    RING16(n_)                           // N2 = sum_m u^2 (W2^T y)_m
    float r = __builtin_amdgcn_rcpf(s_);
    lossacc += corr * n_ * r;
    Yx = ynx * r; Yy = yny * r;          // renorm every step
  }
#undef STZ

  // ---- block reduce + one atomic per block (lossacc same in all lanes) ----
  if (lane == 0) bsum[w] = lossacc;
  __syncthreads();
  if (threadIdx.x == 0)
    atomicAdd(out, (bsum[0] + bsum[1]) + (bsum[2] + bsum[3]));
}

extern "C" void kernel_launch(void* const* d_in, const int* in_sizes, int n_in,
                              void* d_out, int out_size, void* d_ws, size_t ws_size,
                              hipStream_t stream)
{
  (void)in_sizes; (void)n_in; (void)ws_size; (void)d_ws;
  const float* obs2 = (const float*)d_in[0];
  const float* obs1 = (const float*)d_in[1];
  const float* mean = (const float*)d_in[2];
  const float* var  = (const float*)d_in[3];
  const float* bate = (const float*)d_in[4];
  const float* pi   = (const float*)d_in[5];
  const float* aij  = (const float*)d_in[6];
  float* out = (float*)d_out;

  hipMemsetAsync(out, 0, sizeof(float) * out_size, stream);
  k_main<<<NBLK, 256, 0, stream>>>(obs2, obs1, mean, var, bate, pi, aij, out);
}